// Round 1
// baseline (654.753 us; speedup 1.0000x reference)
//
#include <hip/hip_runtime.h>
#include <math.h>

#define Hd 768
#define Bb 8
#define Ll 256
#define Kk 32
#define LG 128

// C[M,N] = A[M,:Kd] @ W[N,:Kd]^T (+bias) (+C if addC)
// A row-major stride lda, W row-major stride ldw, C row-major stride ldc.
// Requires M%64==0, N%64==0, Kd%16==0. Grid: (N/64, M/64), block 256.
__global__ __launch_bounds__(256) void gemm_at(
    const float* __restrict__ A, int lda,
    const float* __restrict__ W, int ldw,
    const float* __restrict__ bias,
    float* __restrict__ C, int ldc,
    int Kd, int addC)
{
    __shared__ float As[16][68];   // k-major, pad to 68 floats (16B-aligned rows)
    __shared__ float Ws[16][68];
    const int t  = threadIdx.x;
    const int tx = t & 15;         // n-dir
    const int ty = t >> 4;         // m-dir
    const int bm = blockIdx.y * 64;
    const int bn = blockIdx.x * 64;

    const int lrow = t >> 2;       // 0..63
    const int lk   = (t & 3) * 4;  // 0,4,8,12
    const float* Arow = A + (size_t)(bm + lrow) * lda + lk;
    const float* Wrow = W + (size_t)(bn + lrow) * ldw + lk;

    float c[4][4] = {};

    for (int k0 = 0; k0 < Kd; k0 += 16) {
        float4 av = *(const float4*)(Arow + k0);
        float4 wv = *(const float4*)(Wrow + k0);
        __syncthreads();           // previous iter's LDS reads done
        As[lk + 0][lrow] = av.x; As[lk + 1][lrow] = av.y;
        As[lk + 2][lrow] = av.z; As[lk + 3][lrow] = av.w;
        Ws[lk + 0][lrow] = wv.x; Ws[lk + 1][lrow] = wv.y;
        Ws[lk + 2][lrow] = wv.z; Ws[lk + 3][lrow] = wv.w;
        __syncthreads();
        #pragma unroll
        for (int kk = 0; kk < 16; ++kk) {
            float4 a = *(const float4*)&As[kk][ty * 4];
            float4 w = *(const float4*)&Ws[kk][tx * 4];
            c[0][0] += a.x * w.x; c[0][1] += a.x * w.y; c[0][2] += a.x * w.z; c[0][3] += a.x * w.w;
            c[1][0] += a.y * w.x; c[1][1] += a.y * w.y; c[1][2] += a.y * w.z; c[1][3] += a.y * w.w;
            c[2][0] += a.z * w.x; c[2][1] += a.z * w.y; c[2][2] += a.z * w.z; c[2][3] += a.z * w.w;
            c[3][0] += a.w * w.x; c[3][1] += a.w * w.y; c[3][2] += a.w * w.z; c[3][3] += a.w * w.w;
        }
    }

    const int row0 = bm + ty * 4;
    const int col  = bn + tx * 4;
    float4 bv = make_float4(0.f, 0.f, 0.f, 0.f);
    if (bias) bv = *(const float4*)&bias[col];
    #pragma unroll
    for (int i = 0; i < 4; ++i) {
        float* cp = C + (size_t)(row0 + i) * ldc + col;
        float4 o = make_float4(c[i][0] + bv.x, c[i][1] + bv.y,
                               c[i][2] + bv.z, c[i][3] + bv.w);
        if (addC) {
            float4 prev = *(const float4*)cp;
            o.x += prev.x; o.y += prev.y; o.z += prev.z; o.w += prev.w;
        }
        *(float4*)cp = o;
    }
}

// One block per (b,l). q: [B*L][768]. kv: [B][128][1536] (k=cols 0..767, v=768..1535).
// gctx: [B*L][768]
__global__ __launch_bounds__(256) void attn_kernel(
    const float* __restrict__ q,
    const float* __restrict__ kv,
    float* __restrict__ gctx)
{
    __shared__ float qs[Hd];
    __shared__ float sc[LG];
    const int t  = threadIdx.x;
    const int bl = blockIdx.x;          // b*L + l
    const int b  = bl >> 8;             // L = 256

    const float* qrow = q + (size_t)bl * Hd;
    qs[t] = qrow[t]; qs[t + 256] = qrow[t + 256]; qs[t + 512] = qrow[t + 512];
    __syncthreads();

    const int wave = t >> 6, lane = t & 63;
    const float* kb = kv + (size_t)b * LG * 1536;

    for (int mi = 0; mi < 32; ++mi) {
        const int m = wave * 32 + mi;
        const float* krow = kb + (size_t)m * 1536;
        float p = 0.f;
        #pragma unroll
        for (int j = 0; j < 12; ++j) p += qs[lane + 64 * j] * krow[lane + 64 * j];
        #pragma unroll
        for (int off = 32; off; off >>= 1) p += __shfl_xor(p, off, 64);
        if (lane == 0) sc[m] = p * 0.03608439182435161f;  // 1/sqrt(768)
    }
    __syncthreads();

    if (wave == 0) {
        float a = sc[lane], bb = sc[lane + 64];
        float mx = fmaxf(a, bb);
        #pragma unroll
        for (int off = 32; off; off >>= 1) mx = fmaxf(mx, __shfl_xor(mx, off, 64));
        float e0 = __expf(a - mx), e1 = __expf(bb - mx);
        float ssum = e0 + e1;
        #pragma unroll
        for (int off = 32; off; off >>= 1) ssum += __shfl_xor(ssum, off, 64);
        float inv = 1.f / ssum;
        sc[lane] = e0 * inv; sc[lane + 64] = e1 * inv;
    }
    __syncthreads();

    float a0 = 0.f, a1 = 0.f, a2 = 0.f;
    const float* vb = kb + Hd;  // v part
    for (int m = 0; m < LG; ++m) {
        const float p = sc[m];
        const float* vrow = vb + (size_t)m * 1536;
        a0 += p * vrow[t];
        a1 += p * vrow[t + 256];
        a2 += p * vrow[t + 512];
    }
    float* grow = gctx + (size_t)bl * Hd;
    grow[t] = a0; grow[t + 256] = a1; grow[t + 512] = a2;
}

__device__ __forceinline__ float sigm(float z) { return 1.f / (1.f + __expf(-z)); }

// h1 = sigmoid(t1) * x + (1 - sigmoid(t1)) * gctx    (t1 already has bg1 added)
// n = number of float4 elements (B*L*768/4)
__global__ __launch_bounds__(256) void gate1_combine(
    const float4* __restrict__ t1, const float4* __restrict__ x,
    const float4* __restrict__ gc, float4* __restrict__ h1)
{
    const int i = blockIdx.x * 256 + threadIdx.x;
    float4 z = t1[i], xv = x[i], gv = gc[i];
    float4 o;
    float g;
    g = sigm(z.x); o.x = g * xv.x + (1.f - g) * gv.x;
    g = sigm(z.y); o.y = g * xv.y + (1.f - g) * gv.y;
    g = sigm(z.z); o.z = g * xv.z + (1.f - g) * gv.z;
    g = sigm(z.w); o.w = g * xv.w + (1.f - g) * gv.w;
    h1[i] = o;
}

// out[b,l,k,h] = sigmoid(D[b,l,h] + E[b,k,h]) * h1[b,l,h] + (1-sig) * s[b,k,h]
// Flat over float4s: f = ((b*L + l)*K + k)*192 + h4
__global__ __launch_bounds__(256) void final_combine(
    const float4* __restrict__ D, const float4* __restrict__ E,
    const float4* __restrict__ h1, const float4* __restrict__ s,
    float4* __restrict__ out)
{
    const int f   = blockIdx.x * 256 + threadIdx.x;
    const int h4  = f % 192;
    const int row = f / 192;        // (b*L+l)*K + k
    const int k   = row & 31;       // K = 32
    const int bl  = row >> 5;
    const int b   = bl >> 8;        // L = 256
    const int bk  = b * Kk + k;

    float4 d  = D[bl * 192 + h4];
    float4 e  = E[bk * 192 + h4];
    float4 hv = h1[bl * 192 + h4];
    float4 sv = s[bk * 192 + h4];
    float4 o;
    float g;
    g = sigm(d.x + e.x); o.x = g * hv.x + (1.f - g) * sv.x;
    g = sigm(d.y + e.y); o.y = g * hv.y + (1.f - g) * sv.y;
    g = sigm(d.z + e.z); o.z = g * hv.z + (1.f - g) * sv.z;
    g = sigm(d.w + e.w); o.w = g * hv.w + (1.f - g) * sv.w;
    out[f] = o;
}

extern "C" void kernel_launch(void* const* d_in, const int* in_sizes, int n_in,
                              void* d_out, int out_size, void* d_ws, size_t ws_size,
                              hipStream_t stream) {
    const float* x   = (const float*)d_in[0];   // (8,256,768)
    const float* s   = (const float*)d_in[1];   // (8,32,768)
    const float* g   = (const float*)d_in[2];   // (8,128,768)
    const float* Wq  = (const float*)d_in[3];   // (768,768)
    const float* bq  = (const float*)d_in[4];
    const float* Wkv = (const float*)d_in[5];   // (1536,768)
    const float* bkv = (const float*)d_in[6];
    const float* Wg1 = (const float*)d_in[7];   // (768,1536)
    const float* bg1 = (const float*)d_in[8];
    const float* Wg2 = (const float*)d_in[9];   // (768,1536)
    const float* bg2 = (const float*)d_in[10];

    float* ws   = (float*)d_ws;
    float* bufA = ws;                 // q -> t1 -> D      (2048*768)
    float* bufB = ws + 1572864;       // kv -> h1          (1024*1536 / 2048*768)
    float* bufC = ws + 3145728;       // gctx -> E         (2048*768)
    float* out  = (float*)d_out;

    const dim3 blk(256);

    // 1) q = x @ Wq^T + bq           -> bufA  [2048,768]
    gemm_at<<<dim3(12, 32), blk, 0, stream>>>(x, Hd, Wq, Hd, bq, bufA, Hd, Hd, 0);
    // 2) kv = g @ Wkv^T + bkv        -> bufB  [1024,1536]
    gemm_at<<<dim3(24, 16), blk, 0, stream>>>(g, Hd, Wkv, Hd, bkv, bufB, 1536, Hd, 0);
    // 3) attention                   -> bufC  [2048,768]
    attn_kernel<<<dim3(Bb * Ll), blk, 0, stream>>>(bufA, bufB, bufC);
    // 4) t1 = x @ Wg1[:, :H]^T + bg1 -> bufA
    gemm_at<<<dim3(12, 32), blk, 0, stream>>>(x, Hd, Wg1, 1536, bg1, bufA, Hd, Hd, 0);
    // 5) t1 += gctx @ Wg1[:, H:]^T
    gemm_at<<<dim3(12, 32), blk, 0, stream>>>(bufC, Hd, Wg1 + Hd, 1536, nullptr, bufA, Hd, Hd, 1);
    // 6) h1 = sig(t1)*x + (1-sig)*gctx -> bufB
    gate1_combine<<<dim3(1536), blk, 0, stream>>>(
        (const float4*)bufA, (const float4*)x, (const float4*)bufC, (float4*)bufB);
    // 7) D = h1 @ Wg2[:, :H]^T + bg2 -> bufA
    gemm_at<<<dim3(12, 32), blk, 0, stream>>>(bufB, Hd, Wg2, 1536, bg2, bufA, Hd, Hd, 0);
    // 8) E = s @ Wg2[:, H:]^T        -> bufC  [256,768]
    gemm_at<<<dim3(12, 4), blk, 0, stream>>>(s, Hd, Wg2 + Hd, 1536, nullptr, bufC, Hd, Hd, 0);
    // 9) out = sig(D+E)*h1 + (1-sig)*s
    final_combine<<<dim3(49152), blk, 0, stream>>>(
        (const float4*)bufA, (const float4*)bufC, (const float4*)bufB,
        (const float4*)s, (float4*)out);
}

// Round 2
// 394.028 us; speedup vs baseline: 1.6617x; 1.6617x over previous
//
#include <hip/hip_runtime.h>
#include <math.h>

#define Hd 768
#define Bb 8
#define Ll 256
#define Kk 32
#define LG 128

using half4  = __attribute__((ext_vector_type(4))) _Float16;
using half8  = __attribute__((ext_vector_type(8))) _Float16;
using f32x4  = __attribute__((ext_vector_type(4))) float;

// ---------------- f32 -> f16 strided row conversion ----------------
// Copies nrows x rowlen (rowlen % 8 == 0) from src (row stride s_row floats)
// to dst (row stride d_row halfs). 8 elements per thread.
__global__ __launch_bounds__(256) void conv_f2h(
    const float* __restrict__ src, int s_row,
    _Float16* __restrict__ dst, int d_row, int rowlen)
{
    const int i   = (blockIdx.x * 256 + threadIdx.x) * 8;
    const int row = i / rowlen;
    const int col = i - row * rowlen;
    const float4* sp = (const float4*)(src + (size_t)row * s_row + col);
    float4 a = sp[0], b = sp[1];
    half8 h;
    h[0] = (_Float16)a.x; h[1] = (_Float16)a.y; h[2] = (_Float16)a.z; h[3] = (_Float16)a.w;
    h[4] = (_Float16)b.x; h[5] = (_Float16)b.y; h[6] = (_Float16)b.z; h[7] = (_Float16)b.w;
    *(half8*)(dst + (size_t)row * d_row + col) = h;
}

// ---------------- f16 MFMA GEMM: C[M,N] = A @ W^T (+bias) ----------------
// A: [M, Kd] halfs, row stride lda. W: [N, Kd] halfs, row stride ldw.
// C: fp32 [M, N], row stride ldc. M%64==0, N%64==0, Kd%64==0.
// Grid (N/64, M/64), block 256 (4 waves, each computes a 16x64 strip).
__global__ __launch_bounds__(256) void gemm_f16(
    const _Float16* __restrict__ A, int lda,
    const _Float16* __restrict__ W, int ldw,
    const float* __restrict__ bias,
    float* __restrict__ C, int ldc, int Kd)
{
    __shared__ _Float16 As[64][72];   // 144 B row stride: 16B-aligned, 2-way-max banks
    __shared__ _Float16 Ws[64][72];

    const int t    = threadIdx.x;
    const int wave = t >> 6;
    const int lane = t & 63;
    const int quad = lane >> 4;
    const int l16  = lane & 15;
    const int bm   = blockIdx.y * 64;
    const int bn   = blockIdx.x * 64;

    // staging assignment: chunk c in [0,512): row=c>>3, koff=(c&7)*8
    const int r0 = t >> 3;            // rows 0..31  (chunk t)
    const int k0off = (t & 7) * 8;    // 0..56
    const _Float16* Ag = A + (size_t)(bm + r0) * lda + k0off;        // row r0
    const _Float16* Ag2 = A + (size_t)(bm + 32 + r0) * lda + k0off;  // row r0+32
    const _Float16* Wg = W + (size_t)(bn + r0) * ldw + k0off;
    const _Float16* Wg2 = W + (size_t)(bn + 32 + r0) * ldw + k0off;

    f32x4 acc[4] = {};

    for (int k0 = 0; k0 < Kd; k0 += 64) {
        half8 a0 = *(const half8*)(Ag + k0);
        half8 a1 = *(const half8*)(Ag2 + k0);
        half8 w0 = *(const half8*)(Wg + k0);
        half8 w1 = *(const half8*)(Wg2 + k0);
        __syncthreads();
        *(half8*)&As[r0][k0off]      = a0;
        *(half8*)&As[32 + r0][k0off] = a1;
        *(half8*)&Ws[r0][k0off]      = w0;
        *(half8*)&Ws[32 + r0][k0off] = w1;
        __syncthreads();
        #pragma unroll
        for (int kk = 0; kk < 2; ++kk) {
            half8 af = *(const half8*)&As[wave * 16 + l16][kk * 32 + quad * 8];
            #pragma unroll
            for (int j = 0; j < 4; ++j) {
                half8 bf = *(const half8*)&Ws[j * 16 + l16][kk * 32 + quad * 8];
                acc[j] = __builtin_amdgcn_mfma_f32_16x16x32_f16(af, bf, acc[j], 0, 0, 0);
            }
        }
    }

    // epilogue: acc[j][reg] -> (m = wave*16 + quad*4 + reg, n = j*16 + l16)
    #pragma unroll
    for (int j = 0; j < 4; ++j) {
        const int col = bn + j * 16 + l16;
        const float bv = bias ? bias[col] : 0.f;
        #pragma unroll
        for (int reg = 0; reg < 4; ++reg) {
            const int row = bm + wave * 16 + quad * 4 + reg;
            C[(size_t)row * ldc + col] = acc[j][reg] + bv;
        }
    }
}

// ---------------- attention: one block per (b,l) ----------------
__global__ __launch_bounds__(256) void attn_kernel(
    const float* __restrict__ q,
    const float* __restrict__ kv,
    float* __restrict__ gctx)
{
    __shared__ float qs[Hd];
    __shared__ float sc[LG];
    const int t  = threadIdx.x;
    const int bl = blockIdx.x;
    const int b  = bl >> 8;

    const float* qrow = q + (size_t)bl * Hd;
    qs[t] = qrow[t]; qs[t + 256] = qrow[t + 256]; qs[t + 512] = qrow[t + 512];
    __syncthreads();

    const int wave = t >> 6, lane = t & 63;
    const float* kb = kv + (size_t)b * LG * 1536;

    for (int mi = 0; mi < 32; ++mi) {
        const int m = wave * 32 + mi;
        const float* krow = kb + (size_t)m * 1536;
        float p = 0.f;
        #pragma unroll
        for (int j = 0; j < 12; ++j) p += qs[lane + 64 * j] * krow[lane + 64 * j];
        #pragma unroll
        for (int off = 32; off; off >>= 1) p += __shfl_xor(p, off, 64);
        if (lane == 0) sc[m] = p * 0.03608439182435161f;
    }
    __syncthreads();

    if (wave == 0) {
        float a = sc[lane], bb = sc[lane + 64];
        float mx = fmaxf(a, bb);
        #pragma unroll
        for (int off = 32; off; off >>= 1) mx = fmaxf(mx, __shfl_xor(mx, off, 64));
        float e0 = __expf(a - mx), e1 = __expf(bb - mx);
        float ssum = e0 + e1;
        #pragma unroll
        for (int off = 32; off; off >>= 1) ssum += __shfl_xor(ssum, off, 64);
        float inv = 1.f / ssum;
        sc[lane] = e0 * inv; sc[lane + 64] = e1 * inv;
    }
    __syncthreads();

    float a0 = 0.f, a1 = 0.f, a2 = 0.f;
    const float* vb = kb + Hd;
    for (int m = 0; m < LG; ++m) {
        const float p = sc[m];
        const float* vrow = vb + (size_t)m * 1536;
        a0 += p * vrow[t];
        a1 += p * vrow[t + 256];
        a2 += p * vrow[t + 512];
    }
    float* grow = gctx + (size_t)bl * Hd;
    grow[t] = a0; grow[t + 256] = a1; grow[t + 512] = a2;
}

__device__ __forceinline__ float sigm(float z) { return 1.f / (1.f + __expf(-z)); }

// h1 = sig(t1)*x + (1-sig(t1))*gctx ; also emits h1 in f16
__global__ __launch_bounds__(256) void gate1_combine(
    const float4* __restrict__ t1, const float4* __restrict__ x,
    const float4* __restrict__ gc, float4* __restrict__ h1,
    _Float16* __restrict__ h16)
{
    const int i = blockIdx.x * 256 + threadIdx.x;
    float4 z = t1[i], xv = x[i], gv = gc[i];
    float4 o;
    float g;
    g = sigm(z.x); o.x = g * xv.x + (1.f - g) * gv.x;
    g = sigm(z.y); o.y = g * xv.y + (1.f - g) * gv.y;
    g = sigm(z.z); o.z = g * xv.z + (1.f - g) * gv.z;
    g = sigm(z.w); o.w = g * xv.w + (1.f - g) * gv.w;
    h1[i] = o;
    half4 h;
    h[0] = (_Float16)o.x; h[1] = (_Float16)o.y; h[2] = (_Float16)o.z; h[3] = (_Float16)o.w;
    *(half4*)(h16 + (size_t)i * 4) = h;
}

// out[b,l,k,h] = sig(D[b,l,h]+E[b,k,h]) * h1[b,l,h] + (1-sig) * s[b,k,h]
__global__ __launch_bounds__(256) void final_combine(
    const float4* __restrict__ D, const float4* __restrict__ E,
    const float4* __restrict__ h1, const float4* __restrict__ s,
    float4* __restrict__ out)
{
    const int f   = blockIdx.x * 256 + threadIdx.x;
    const int h4  = f % 192;
    const int row = f / 192;
    const int k   = row & 31;
    const int bl  = row >> 5;
    const int b   = bl >> 8;
    const int bk  = b * Kk + k;

    float4 d  = D[bl * 192 + h4];
    float4 e  = E[bk * 192 + h4];
    float4 hv = h1[bl * 192 + h4];
    float4 sv = s[bk * 192 + h4];
    float4 o;
    float g;
    g = sigm(d.x + e.x); o.x = g * hv.x + (1.f - g) * sv.x;
    g = sigm(d.y + e.y); o.y = g * hv.y + (1.f - g) * sv.y;
    g = sigm(d.z + e.z); o.z = g * hv.z + (1.f - g) * sv.z;
    g = sigm(d.w + e.w); o.w = g * hv.w + (1.f - g) * sv.w;
    out[f] = o;
}

extern "C" void kernel_launch(void* const* d_in, const int* in_sizes, int n_in,
                              void* d_out, int out_size, void* d_ws, size_t ws_size,
                              hipStream_t stream) {
    const float* x   = (const float*)d_in[0];
    const float* s   = (const float*)d_in[1];
    const float* g   = (const float*)d_in[2];
    const float* Wq  = (const float*)d_in[3];
    const float* bq  = (const float*)d_in[4];
    const float* Wkv = (const float*)d_in[5];
    const float* bkv = (const float*)d_in[6];
    const float* Wg1 = (const float*)d_in[7];
    const float* bg1 = (const float*)d_in[8];
    const float* Wg2 = (const float*)d_in[9];
    const float* bg2 = (const float*)d_in[10];

    char* w = (char*)d_ws;
    // fp32 buffers (6.29 MB each)
    float* bufA = (float*)(w);                    // q -> t1 -> D
    float* bufB = (float*)(w + 6815744);          // kv -> h1
    float* bufC = (float*)(w + 13631488);         // gctx -> E
    // f16 buffers
    _Float16* xg16   = (_Float16*)(w + 20447232); // [2048][1536]: cols 0..767 = x, 768.. = gctx
    _Float16* g16    = (_Float16*)(w + 26738688); // [1024][768]
    _Float16* s16    = (_Float16*)(w + 28311552); // [256][768]
    _Float16* h116   = (_Float16*)(w + 28704768); // [2048][768]
    _Float16* Wq16   = (_Float16*)(w + 31850496); // [768][768]
    _Float16* Wkv16  = (_Float16*)(w + 33030144); // [1536][768]
    _Float16* Wg116  = (_Float16*)(w + 35389440); // [768][1536]
    _Float16* Wg2a16 = (_Float16*)(w + 37748736); // [768][768]
    _Float16* Wg2b16 = (_Float16*)(w + 38928384); // [768][768]
    float* out = (float*)d_out;

    const dim3 blk(256);

    // --- conversions (f32 -> f16) ---
    conv_f2h<<<dim3(768), blk, 0, stream>>>(x, 768, xg16, 1536, 768);          // x -> xg cols 0..767
    conv_f2h<<<dim3(384), blk, 0, stream>>>(g, 768, g16, 768, 768);
    conv_f2h<<<dim3(96),  blk, 0, stream>>>(s, 768, s16, 768, 768);
    conv_f2h<<<dim3(288), blk, 0, stream>>>(Wq, 768, Wq16, 768, 768);
    conv_f2h<<<dim3(576), blk, 0, stream>>>(Wkv, 768, Wkv16, 768, 768);
    conv_f2h<<<dim3(576), blk, 0, stream>>>(Wg1, 1536, Wg116, 1536, 1536);
    conv_f2h<<<dim3(288), blk, 0, stream>>>(Wg2, 1536, Wg2a16, 768, 768);
    conv_f2h<<<dim3(288), blk, 0, stream>>>(Wg2 + 768, 1536, Wg2b16, 768, 768);

    // 1) q = x @ Wq^T + bq  -> bufA [2048,768]
    gemm_f16<<<dim3(12, 32), blk, 0, stream>>>(xg16, 1536, Wq16, 768, bq, bufA, 768, 768);
    // 2) kv = g @ Wkv^T + bkv -> bufB [1024,1536]
    gemm_f16<<<dim3(24, 16), blk, 0, stream>>>(g16, 768, Wkv16, 768, bkv, bufB, 1536, 768);
    // 3) attention -> bufC [2048,768]
    attn_kernel<<<dim3(Bb * Ll), blk, 0, stream>>>(bufA, bufB, bufC);
    // 4) gctx -> xg16 cols 768..1535
    conv_f2h<<<dim3(768), blk, 0, stream>>>(bufC, 768, xg16 + 768, 1536, 768);
    // 5) t1 = [x|gctx] @ Wg1^T + bg1  (K=1536) -> bufA
    gemm_f16<<<dim3(12, 32), blk, 0, stream>>>(xg16, 1536, Wg116, 1536, bg1, bufA, 768, 1536);
    // 6) h1 = sig(t1)*x + (1-sig)*gctx -> bufB (fp32) + h116 (f16)
    gate1_combine<<<dim3(1536), blk, 0, stream>>>(
        (const float4*)bufA, (const float4*)x, (const float4*)bufC, (float4*)bufB, h116);
    // 7) D = h1 @ Wg2a^T + bg2 -> bufA
    gemm_f16<<<dim3(12, 32), blk, 0, stream>>>(h116, 768, Wg2a16, 768, bg2, bufA, 768, 768);
    // 8) E = s @ Wg2b^T -> bufC [256,768]
    gemm_f16<<<dim3(12, 4), blk, 0, stream>>>(s16, 768, Wg2b16, 768, nullptr, bufC, 768, 768);
    // 9) out = sig(D+E)*h1 + (1-sig)*s
    final_combine<<<dim3(49152), blk, 0, stream>>>(
        (const float4*)bufA, (const float4*)bufC, (const float4*)bufB,
        (const float4*)s, (float4*)out);
}

// Round 3
// 357.482 us; speedup vs baseline: 1.8316x; 1.1022x over previous
//
#include <hip/hip_runtime.h>
#include <math.h>

#define Hd 768
#define Bb 8
#define Ll 256
#define Kk 32
#define LG 128

using half4 = __attribute__((ext_vector_type(4))) _Float16;
using half8 = __attribute__((ext_vector_type(8))) _Float16;
using f32x4 = __attribute__((ext_vector_type(4))) float;

// ---------------- multi-segment f32 -> f16 conversion (one dispatch) -----------
struct ConvArgs {
    const float* src[8];
    _Float16*    dst[8];
    int cum[9];     // cumulative chunk counts (chunks of 8 elements)
    int sstr[8];    // src row stride (elements)
    int dstr[8];    // dst row stride (elements)
    int rl[8];      // row length (elements, %8==0)
};

__global__ __launch_bounds__(256) void conv_multi(ConvArgs a) {
    int c = blockIdx.x * 256 + threadIdx.x;
    if (c >= a.cum[8]) return;
    int s = 0;
    while (c >= a.cum[s + 1]) ++s;
    const int lc  = c - a.cum[s];
    const unsigned cpr = (unsigned)(a.rl[s] >> 3);
    const unsigned row = (unsigned)lc / cpr;
    const int col = (lc - (int)(row * cpr)) * 8;
    const float* sp = a.src[s] + (size_t)row * a.sstr[s] + col;
    float4 v0 = *(const float4*)sp;
    float4 v1 = *(const float4*)(sp + 4);
    half8 h;
    h[0] = (_Float16)v0.x; h[1] = (_Float16)v0.y; h[2] = (_Float16)v0.z; h[3] = (_Float16)v0.w;
    h[4] = (_Float16)v1.x; h[5] = (_Float16)v1.y; h[6] = (_Float16)v1.z; h[7] = (_Float16)v1.w;
    *(half8*)(a.dst[s] + (size_t)row * a.dstr[s] + col) = h;
}

// ---------------- f16 MFMA GEMM: C[M,N] = A @ W^T (+bias) ----------------------
// Block tile 128x64, 4 waves, each wave 32 rows x 64 cols. Kd%64==0, M%128==0,
// N%64==0. Batched via blockIdx.z (element strides sA,sW,sC,sC2).
// Outputs: C fp32 (if non-null), C2 f16 (if non-null). kvsplit=1: cols<768 ->
// K16[row][col], cols>=768 -> VT16[b][col-768][row&127] (b=row>>7).
__global__ __launch_bounds__(256) void gemm_f16(
    const _Float16* __restrict__ A, int lda, long sA,
    const _Float16* __restrict__ W, int ldw, long sW,
    const float* __restrict__ bias,
    float* __restrict__ C, int ldc, long sC,
    _Float16* __restrict__ C2, int ldc2, long sC2,
    int Kd, int kvsplit,
    _Float16* __restrict__ K16, _Float16* __restrict__ VT16)
{
    __shared__ _Float16 As[128][72];   // 144 B rows: 16B-aligned, benign banking
    __shared__ _Float16 Ws[64][72];

    const int t    = threadIdx.x;
    const int w    = t >> 6;
    const int lane = t & 63;
    const int quad = lane >> 4;
    const int l16  = lane & 15;
    const int bm   = blockIdx.y * 128;
    const int bn   = blockIdx.x * 64;
    const int z    = blockIdx.z;
    A += (size_t)z * sA;
    W += (size_t)z * sW;

    const int sr = t >> 3;          // 0..31
    const int sk = (t & 7) * 8;     // 0,8,..,56

    f32x4 acc[2][4] = {};

    for (int k0 = 0; k0 < Kd; k0 += 64) {
        half8 av[4], wv[2];
        #pragma unroll
        for (int i = 0; i < 4; ++i)
            av[i] = *(const half8*)(A + (size_t)(bm + i * 32 + sr) * lda + k0 + sk);
        #pragma unroll
        for (int i = 0; i < 2; ++i)
            wv[i] = *(const half8*)(W + (size_t)(bn + i * 32 + sr) * ldw + k0 + sk);
        __syncthreads();
        #pragma unroll
        for (int i = 0; i < 4; ++i) *(half8*)&As[i * 32 + sr][sk] = av[i];
        #pragma unroll
        for (int i = 0; i < 2; ++i) *(half8*)&Ws[i * 32 + sr][sk] = wv[i];
        __syncthreads();
        #pragma unroll
        for (int kk = 0; kk < 2; ++kk) {
            half8 af[2], bf[4];
            af[0] = *(const half8*)&As[w * 32 + l16][kk * 32 + quad * 8];
            af[1] = *(const half8*)&As[w * 32 + 16 + l16][kk * 32 + quad * 8];
            #pragma unroll
            for (int j = 0; j < 4; ++j)
                bf[j] = *(const half8*)&Ws[j * 16 + l16][kk * 32 + quad * 8];
            #pragma unroll
            for (int rt = 0; rt < 2; ++rt)
                #pragma unroll
                for (int j = 0; j < 4; ++j)
                    acc[rt][j] = __builtin_amdgcn_mfma_f32_16x16x32_f16(
                        af[rt], bf[j], acc[rt][j], 0, 0, 0);
        }
    }

    #pragma unroll
    for (int rt = 0; rt < 2; ++rt) {
        #pragma unroll
        for (int j = 0; j < 4; ++j) {
            const int col  = bn + j * 16 + l16;
            const int row0 = bm + w * 32 + rt * 16 + quad * 4;
            const float bv = bias ? bias[col] : 0.f;
            if (kvsplit) {
                if (col < 768) {
                    #pragma unroll
                    for (int r = 0; r < 4; ++r)
                        K16[(size_t)(row0 + r) * 768 + col] = (_Float16)(acc[rt][j][r] + bv);
                } else {
                    const int b = row0 >> 7, h = col - 768, m0 = row0 & 127;
                    half4 hv;
                    #pragma unroll
                    for (int r = 0; r < 4; ++r) hv[r] = (_Float16)(acc[rt][j][r] + bv);
                    *(half4*)(VT16 + ((size_t)(b * 768 + h)) * 128 + m0) = hv;
                }
            } else {
                #pragma unroll
                for (int r = 0; r < 4; ++r) {
                    const float v = acc[rt][j][r] + bv;
                    const size_t rr = (size_t)(row0 + r);
                    if (C)  C[(size_t)z * sC + rr * ldc + col] = v;
                    if (C2) C2[(size_t)z * sC2 + rr * ldc2 + col] = (_Float16)v;
                }
            }
        }
    }
}

// ---------------- softmax over rows of 128 (scaled) ----------------------------
__global__ __launch_bounds__(256) void softmax_rows(
    const float* __restrict__ sc, _Float16* __restrict__ P)
{
    const int wave = threadIdx.x >> 6, lane = threadIdx.x & 63;
    const int r = blockIdx.x * 4 + wave;
    const float* row = sc + (size_t)r * 128;
    const float scale = 0.03608439182435161f;   // 1/sqrt(768)
    float a = row[lane] * scale, b = row[lane + 64] * scale;
    float mx = fmaxf(a, b);
    #pragma unroll
    for (int off = 32; off; off >>= 1) mx = fmaxf(mx, __shfl_xor(mx, off, 64));
    float e0 = __expf(a - mx), e1 = __expf(b - mx);
    float s = e0 + e1;
    #pragma unroll
    for (int off = 32; off; off >>= 1) s += __shfl_xor(s, off, 64);
    const float inv = 1.f / s;
    P[(size_t)r * 128 + lane]      = (_Float16)(e0 * inv);
    P[(size_t)r * 128 + lane + 64] = (_Float16)(e1 * inv);
}

__device__ __forceinline__ float sigm(float z) { return 1.f / (1.f + __expf(-z)); }

// h1 = sig(t1)*x + (1-sig)*gctx ; fp32 out + f16 copy
__global__ __launch_bounds__(256) void gate1_combine(
    const float4* __restrict__ t1, const float4* __restrict__ x,
    const float4* __restrict__ gc, float4* __restrict__ h1,
    _Float16* __restrict__ h16)
{
    const int i = blockIdx.x * 256 + threadIdx.x;
    float4 z = t1[i], xv = x[i], gv = gc[i];
    float4 o;
    float g;
    g = sigm(z.x); o.x = g * xv.x + (1.f - g) * gv.x;
    g = sigm(z.y); o.y = g * xv.y + (1.f - g) * gv.y;
    g = sigm(z.z); o.z = g * xv.z + (1.f - g) * gv.z;
    g = sigm(z.w); o.w = g * xv.w + (1.f - g) * gv.w;
    h1[i] = o;
    half4 h;
    h[0] = (_Float16)o.x; h[1] = (_Float16)o.y; h[2] = (_Float16)o.z; h[3] = (_Float16)o.w;
    *(half4*)(h16 + (size_t)i * 4) = h;
}

// out[b,l,k,h] = sig(D[b,l,h]+E[b,k,h]) * h1[b,l,h] + (1-sig) * s[b,k,h]
__global__ __launch_bounds__(256) void final_combine(
    const float4* __restrict__ D, const float4* __restrict__ E,
    const float4* __restrict__ h1, const float4* __restrict__ s,
    float4* __restrict__ out)
{
    const int f   = blockIdx.x * 256 + threadIdx.x;
    const int h4  = f % 192;
    const int row = f / 192;
    const int k   = row & 31;
    const int bl  = row >> 5;
    const int b   = bl >> 8;
    const int bk  = b * Kk + k;

    float4 d  = D[bl * 192 + h4];
    float4 e  = E[bk * 192 + h4];
    float4 hv = h1[bl * 192 + h4];
    float4 sv = s[bk * 192 + h4];
    float4 o;
    float g;
    g = sigm(d.x + e.x); o.x = g * hv.x + (1.f - g) * sv.x;
    g = sigm(d.y + e.y); o.y = g * hv.y + (1.f - g) * sv.y;
    g = sigm(d.z + e.z); o.z = g * hv.z + (1.f - g) * sv.z;
    g = sigm(d.w + e.w); o.w = g * hv.w + (1.f - g) * sv.w;
    out[f] = o;
}

extern "C" void kernel_launch(void* const* d_in, const int* in_sizes, int n_in,
                              void* d_out, int out_size, void* d_ws, size_t ws_size,
                              hipStream_t stream) {
    const float* x   = (const float*)d_in[0];
    const float* s   = (const float*)d_in[1];
    const float* g   = (const float*)d_in[2];
    const float* Wq  = (const float*)d_in[3];
    const float* bq  = (const float*)d_in[4];
    const float* Wkv = (const float*)d_in[5];
    const float* bkv = (const float*)d_in[6];
    const float* Wg1 = (const float*)d_in[7];
    const float* bg1 = (const float*)d_in[8];
    const float* Wg2 = (const float*)d_in[9];
    const float* bg2 = (const float*)d_in[10];

    char* w = (char*)d_ws;
    // fp32 buffers
    float* bufA = (float*)(w);                    // t1 -> D; also sc32 + P16 early
    float* bufB = (float*)(w + 6291456);          // h1; also Wq16/Wkv16/Wg116 early
    float* bufC = (float*)(w + 12582912);         // gctx fp32
    float* sc32 = (float*)(w);                    // [2048][128] (in bufA, early)
    _Float16* P16 = (_Float16*)(w + 1048576);     // [2048][128] (in bufA, early)
    // f16 buffers
    _Float16* xg16   = (_Float16*)(w + 18874368); // [2048][1536]: x | gctx16
    _Float16* g16    = (_Float16*)(w + 25165824); // [1024][768]
    _Float16* s16    = (_Float16*)(w + 26738688); // [256][768]
    _Float16* q16    = (_Float16*)(w + 27131904); // [2048][768]; later h116
    _Float16* h116   = (_Float16*)(w + 27131904);
    _Float16* k16    = (_Float16*)(w + 30277632); // [1024][768]; later bufE
    float*    bufE   = (float*)(w + 30277632);    // [256][768] fp32
    _Float16* vT16   = (_Float16*)(w + 31850496); // [8][768][128]
    // f16 weights live in bufB's region until gate1 overwrites it
    _Float16* Wq16   = (_Float16*)(w + 6291456);  // [768][768]
    _Float16* Wkv16  = (_Float16*)(w + 7471104);  // [1536][768]
    _Float16* Wg116  = (_Float16*)(w + 9830400);  // [768][1536]
    _Float16* Wg2a16 = (_Float16*)(w + 33423360); // [768][768]
    _Float16* Wg2b16 = (_Float16*)(w + 34603008); // [768][768]
    float* out = (float*)d_out;

    const dim3 blk(256);

    // 1) all f32->f16 conversions in one dispatch
    ConvArgs ca;
    ca.src[0] = x;         ca.dst[0] = xg16;   ca.sstr[0] = 768;  ca.dstr[0] = 1536; ca.rl[0] = 768;
    ca.src[1] = g;         ca.dst[1] = g16;    ca.sstr[1] = 768;  ca.dstr[1] = 768;  ca.rl[1] = 768;
    ca.src[2] = s;         ca.dst[2] = s16;    ca.sstr[2] = 768;  ca.dstr[2] = 768;  ca.rl[2] = 768;
    ca.src[3] = Wq;        ca.dst[3] = Wq16;   ca.sstr[3] = 768;  ca.dstr[3] = 768;  ca.rl[3] = 768;
    ca.src[4] = Wkv;       ca.dst[4] = Wkv16;  ca.sstr[4] = 768;  ca.dstr[4] = 768;  ca.rl[4] = 768;
    ca.src[5] = Wg1;       ca.dst[5] = Wg116;  ca.sstr[5] = 1536; ca.dstr[5] = 1536; ca.rl[5] = 1536;
    ca.src[6] = Wg2;       ca.dst[6] = Wg2a16; ca.sstr[6] = 1536; ca.dstr[6] = 768;  ca.rl[6] = 768;
    ca.src[7] = Wg2 + 768; ca.dst[7] = Wg2b16; ca.sstr[7] = 1536; ca.dstr[7] = 768;  ca.rl[7] = 768;
    ca.cum[0] = 0;      ca.cum[1] = 196608; ca.cum[2] = 294912; ca.cum[3] = 319488;
    ca.cum[4] = 393216; ca.cum[5] = 540672; ca.cum[6] = 688128; ca.cum[7] = 761856;
    ca.cum[8] = 835584;
    conv_multi<<<dim3(3264), blk, 0, stream>>>(ca);

    // 2) q16 = f16(x @ Wq^T + bq)
    gemm_f16<<<dim3(12, 16, 1), blk, 0, stream>>>(
        xg16, 1536, 0, Wq16, 768, 0, bq,
        nullptr, 0, 0, q16, 768, 0, 768, 0, nullptr, nullptr);
    // 3) kv = g @ Wkv^T + bkv  -> k16 [b][m][h], vT16 [b][h][m]
    gemm_f16<<<dim3(24, 8, 1), blk, 0, stream>>>(
        g16, 768, 0, Wkv16, 768, 0, bkv,
        nullptr, 0, 0, nullptr, 0, 0, 768, 1, k16, vT16);
    // 4) scores = q @ k^T (batched over b) -> sc32 [2048][128]
    gemm_f16<<<dim3(2, 2, 8), blk, 0, stream>>>(
        q16, 768, 256L * 768, k16, 768, 128L * 768, nullptr,
        sc32, 128, 256L * 128, nullptr, 0, 0, 768, 0, nullptr, nullptr);
    // 5) softmax rows -> P16
    softmax_rows<<<dim3(512), blk, 0, stream>>>(sc32, P16);
    // 6) gctx = P @ v (batched) -> bufC fp32 + xg16 cols 768.. f16
    gemm_f16<<<dim3(12, 2, 8), blk, 0, stream>>>(
        P16, 128, 256L * 128, vT16, 128, 768L * 128, nullptr,
        bufC, 768, 256L * 768, xg16 + 768, 1536, 256L * 1536, 128, 0, nullptr, nullptr);
    // 7) t1 = [x|gctx] @ Wg1^T + bg1 -> bufA
    gemm_f16<<<dim3(12, 16, 1), blk, 0, stream>>>(
        xg16, 1536, 0, Wg116, 1536, 0, bg1,
        bufA, 768, 0, nullptr, 0, 0, 1536, 0, nullptr, nullptr);
    // 8) h1 = sig(t1)*x + (1-sig)*gctx -> bufB fp32 + h116 f16
    gate1_combine<<<dim3(1536), blk, 0, stream>>>(
        (const float4*)bufA, (const float4*)x, (const float4*)bufC, (float4*)bufB, h116);
    // 9) D = h1 @ Wg2a^T + bg2 -> bufA
    gemm_f16<<<dim3(12, 16, 1), blk, 0, stream>>>(
        h116, 768, 0, Wg2a16, 768, 0, bg2,
        bufA, 768, 0, nullptr, 0, 0, 768, 0, nullptr, nullptr);
    // 10) E = s @ Wg2b^T -> bufE
    gemm_f16<<<dim3(12, 2, 1), blk, 0, stream>>>(
        s16, 768, 0, Wg2b16, 768, 0, nullptr,
        bufE, 768, 0, nullptr, 0, 0, 768, 0, nullptr, nullptr);
    // 11) out = sig(D+E)*h1 + (1-sig)*s
    final_combine<<<dim3(49152), blk, 0, stream>>>(
        (const float4*)bufA, (const float4*)bufE, (const float4*)bufB,
        (const float4*)s, (float4*)out);
}